// Round 6
// baseline (236.667 us; speedup 1.0000x reference)
//
#include <hip/hip_runtime.h>
#include <hip/hip_bf16.h>

#define NT 768
#define ND 256
#define PD 128
#define NH 8
#define DH 32
#define NPAIR 589824   // 768*768

// workspace offsets (floats)
#define WS_X     0
#define WS_Q     196608
#define WS_K     393216
#define WS_V     589824
#define WS_GATE  786432
#define WS_AOUT  983040
#define WS_BIAS  1179648
#define WS_WPT   5898240   // 1024 floats: wpt[h][e] = ln_w[e]*wb[e][h]
#define WS_C01   5899264   // c0[0..7], c1[0..7]
// total = 5899280 floats = 23.6 MB

typedef float f32x2 __attribute__((ext_vector_type(2)));
typedef float f32x4 __attribute__((ext_vector_type(4)));
static __device__ __forceinline__ f32x2 pkfma(f32x2 a, f32x2 b, f32x2 c) {
  return __builtin_elementwise_fma(a, b, c);
}

// ---------------- K0: precompute WPT, C0, C1 (one block) ----------------
__global__ __launch_bounds__(256) void k_prep(const float* __restrict__ lnw,
                                              const float* __restrict__ lnb,
                                              const float* __restrict__ wb,
                                              float* __restrict__ wpt,
                                              float* __restrict__ c01) {
  __shared__ float PS0[256], PS1[256];
  int t = threadIdx.x;
#pragma unroll
  for (int i = 0; i < 4; ++i) {
    int idx = t + 256 * i;
    int h = idx >> 7, e = idx & 127;
    wpt[h * 128 + e] = lnw[e] * wb[e * 8 + h];
  }
  int h = t & 7, seg = t >> 3;          // seg 0..31 covers e = 4*seg..+3
  float a0 = 0.f, a1 = 0.f;
#pragma unroll
  for (int k = 0; k < 4; ++k) {
    int e = seg * 4 + k;
    float wv = wb[e * 8 + h];
    a0 = fmaf(lnb[e], wv, a0);
    a1 = fmaf(lnw[e], wv, a1);
  }
  PS0[t] = a0; PS1[t] = a1;
  __syncthreads();
  if (t < 16) {
    int hh = t & 7; bool isc1 = t >= 8;
    float s = 0.f;
    for (int sg = 0; sg < 32; ++sg) s += (isc1 ? PS1 : PS0)[sg * 8 + hh];
    c01[t] = s;
  }
}

// ---------------- K1: LayerNorm(node) -> x ----------------
__global__ __launch_bounds__(256) void k_ln_node(const float* __restrict__ nf,
                                                 const float* __restrict__ w,
                                                 const float* __restrict__ b,
                                                 float* __restrict__ x) {
  int i = blockIdx.x, t = threadIdx.x;
  float v = nf[i * ND + t];
  float s1 = v, s2 = v * v;
#pragma unroll
  for (int m = 1; m < 64; m <<= 1) { s1 += __shfl_xor(s1, m); s2 += __shfl_xor(s2, m); }
  __shared__ float a1[4], a2[4];
  if ((t & 63) == 0) { a1[t >> 6] = s1; a2[t >> 6] = s2; }
  __syncthreads();
  s1 = a1[0] + a1[1] + a1[2] + a1[3];
  s2 = a2[0] + a2[1] + a2[2] + a2[3];
  float mu = s1 * (1.f / ND);
  float var = s2 * (1.f / ND) - mu * mu;
  float rs = rsqrtf(var + 1e-5f);
  x[i * ND + t] = (v - mu) * rs * w[t] + b[t];
}

// ---------------- K2: x @ [w_qkv | w_g] -> q,k,v (h,i,d) + sigmoid gate ----------------
__global__ __launch_bounds__(256) void k_qkvg(const float* __restrict__ x,
                                              const float* __restrict__ wqkv,
                                              const float* __restrict__ wg,
                                              const float* __restrict__ bg,
                                              float* __restrict__ ws) {
  __shared__ __align__(16) float As[16 * 64];
  __shared__ __align__(16) float Bs[16 * 64];
  int n0 = blockIdx.x * 64, i0 = blockIdx.y * 64, t = threadIdx.x;
  bool isg = (n0 >= 768);
  const float* W = isg ? wg : wqkv;
  int ldb = isg ? 256 : 768;
  int nc0 = isg ? n0 - 768 : n0;
  int tm = t >> 4, tn = t & 15;
  int sm = t >> 2, sk = (t & 3) * 4;
  int bk = t >> 4, bn = (t & 15) * 4;
  float acc[4][4] = {{0.f}};
  for (int k0 = 0; k0 < 256; k0 += 16) {
    float4 av = *(const float4*)&x[(i0 + sm) * 256 + k0 + sk];
    float4 bv = *(const float4*)&W[(size_t)(k0 + bk) * ldb + nc0 + bn];
    __syncthreads();
    As[(sk + 0) * 64 + sm] = av.x; As[(sk + 1) * 64 + sm] = av.y;
    As[(sk + 2) * 64 + sm] = av.z; As[(sk + 3) * 64 + sm] = av.w;
    *(float4*)&Bs[bk * 64 + bn] = bv;
    __syncthreads();
#pragma unroll
    for (int kk = 0; kk < 16; ++kk) {
      float4 a4 = *(float4*)&As[kk * 64 + tm * 4];
      float4 b4 = *(float4*)&Bs[kk * 64 + tn * 4];
      float ar[4] = {a4.x, a4.y, a4.z, a4.w};
      float br[4] = {b4.x, b4.y, b4.z, b4.w};
#pragma unroll
      for (int ii = 0; ii < 4; ++ii)
#pragma unroll
        for (int jj = 0; jj < 4; ++jj) acc[ii][jj] = fmaf(ar[ii], br[jj], acc[ii][jj]);
    }
  }
#pragma unroll
  for (int ii = 0; ii < 4; ++ii) {
    int i = i0 + tm * 4 + ii;
#pragma unroll
    for (int jj = 0; jj < 4; ++jj) {
      int o = n0 + tn * 4 + jj;
      float val = acc[ii][jj];
      if (!isg) {
        int which = o >> 8, inner = o & 255, h = inner >> 5, d = inner & 31;
        float* dst = ws + (which == 0 ? WS_Q : (which == 1 ? WS_K : WS_V));
        float sc = (which == 0) ? 0.17677669529663687f : 1.f;  // 1/sqrt(32) on q
        dst[(h * NT + i) * DH + d] = val * sc;
      } else {
        int inner = nc0 + tn * 4 + jj;
        val += bg[inner];
        ws[WS_GATE + i * ND + inner] = 1.f / (1.f + __expf(-val));
      }
    }
  }
}

// ---------------- K3: fused LN(pair) @ w_bias + mask fold -> bias (h,i,j) ----------------
// v4: v3 layout (16 lanes/row x 4 rows/wave-instr, reg-resident wpt, packed fma,
// 4-step butterfly) + 256-VGPR budget (no spill) + explicit 2-deep prefetch.
__global__ __launch_bounds__(256, 2) void k_pair_bias(const float* __restrict__ pf,
                                                      const int* __restrict__ mask,
                                                      const float* __restrict__ wpt,
                                                      const float* __restrict__ c01,
                                                      float* __restrict__ bias_out) {
  __shared__ float OB[4][8 * 65];       // per-wave: 8 heads x 64 rows (pad 65)
  int t = threadIdx.x;
  int w = t >> 6, lane = t & 63;
  int c = lane & 15;                    // channel-lane: float4 chunks {c, c+16}
  int g = lane >> 4;                    // row group 0..3
  size_t wbase = ((size_t)blockIdx.x * 4 + w) * 64;   // this wave's 64 rows
  int hme = (lane >> 1) & 7;            // head this lane owns after reduction
  // preload wpt slices for this lane's 8 channels, all 8 heads (64 VGPR)
  f32x2 b0[8], b1[8], b2[8], b3[8];
#pragma unroll
  for (int h = 0; h < 8; ++h) {
    float4 w0 = *(const float4*)(wpt + h * 128 + c * 4);
    float4 w1 = *(const float4*)(wpt + h * 128 + (c + 16) * 4);
    b0[h] = (f32x2){w0.x, w0.y}; b1[h] = (f32x2){w0.z, w0.w};
    b2[h] = (f32x2){w1.x, w1.y}; b3[h] = (f32x2){w1.z, w1.w};
  }
  float c0me = c01[hme], c1me = c01[8 + hme];
  bool bit3 = (lane & 8) != 0, bit2 = (lane & 4) != 0, bit1 = (lane & 2) != 0;
  const float* pbase = pf + wbase * 128;
  // 2-deep software prefetch
  float4 pa0 = *(const float4*)(pbase + (size_t)(0 * 4 + g) * 128 + c * 4);
  float4 pa1 = *(const float4*)(pbase + (size_t)(0 * 4 + g) * 128 + (c + 16) * 4);
  float4 pb0 = *(const float4*)(pbase + (size_t)(1 * 4 + g) * 128 + c * 4);
  float4 pb1 = *(const float4*)(pbase + (size_t)(1 * 4 + g) * 128 + (c + 16) * 4);
#pragma unroll
  for (int it = 0; it < 16; ++it) {
    float4 p0 = pa0, p1 = pa1;
    pa0 = pb0; pa1 = pb1;
    if (it < 14) {
      pb0 = *(const float4*)(pbase + (size_t)((it + 2) * 4 + g) * 128 + c * 4);
      pb1 = *(const float4*)(pbase + (size_t)((it + 2) * 4 + g) * 128 + (c + 16) * 4);
    }
    int r = it * 4 + g;                 // row within wave's 64
    f32x2 a0 = (f32x2){p0.x, p0.y}, a1 = (f32x2){p0.z, p0.w};
    f32x2 a2 = (f32x2){p1.x, p1.y}, a3 = (f32x2){p1.z, p1.w};
    f32x2 sv1 = a0 + a1 + a2 + a3;
    f32x2 sv2 = pkfma(a0, a0, pkfma(a1, a1, pkfma(a2, a2, pkfma(a3, a3, (f32x2){0.f, 0.f}))));
    float s1 = sv1.x + sv1.y;
    float s2 = sv2.x + sv2.y;
    float d[8];
#pragma unroll
    for (int h = 0; h < 8; ++h) {
      f32x2 acc = pkfma(a0, b0[h], pkfma(a1, b1[h], pkfma(a2, b2[h], pkfma(a3, b3[h], (f32x2){0.f, 0.f}))));
      d[h] = acc.x + acc.y;
    }
    // butterfly: reduce over 16 lanes while splitting 8 heads across lanes
    float m0, m1, m2, m3;
    m0 = (bit3 ? d[4] : d[0]) + __shfl_xor(bit3 ? d[0] : d[4], 8);
    m1 = (bit3 ? d[5] : d[1]) + __shfl_xor(bit3 ? d[1] : d[5], 8);
    m2 = (bit3 ? d[6] : d[2]) + __shfl_xor(bit3 ? d[2] : d[6], 8);
    m3 = (bit3 ? d[7] : d[3]) + __shfl_xor(bit3 ? d[3] : d[7], 8);
    float n0, n1;
    n0 = (bit2 ? m2 : m0) + __shfl_xor(bit2 ? m0 : m2, 4);
    n1 = (bit2 ? m3 : m1) + __shfl_xor(bit2 ? m1 : m3, 4);
    float o = (bit1 ? n1 : n0) + __shfl_xor(bit1 ? n0 : n1, 2);
    o += __shfl_xor(o, 1);
    s1 += __shfl_xor(s1, 1); s1 += __shfl_xor(s1, 2);
    s1 += __shfl_xor(s1, 4); s1 += __shfl_xor(s1, 8);
    s2 += __shfl_xor(s2, 1); s2 += __shfl_xor(s2, 2);
    s2 += __shfl_xor(s2, 4); s2 += __shfl_xor(s2, 8);
    float mu = s1 * (1.f / 128.f);
    float var = s2 * (1.f / 128.f) - mu * mu;
    float rs = rsqrtf(var + 1e-5f);
    float bv = rs * (o - mu * c1me) + c0me;
    if ((lane & 1) == 0) OB[w][hme * 65 + r] = bv;
  }
  // final phase: mask fold + coalesced per-head stores (wave-private, no barrier)
  int mk = mask[wbase + lane];
#pragma unroll
  for (int h = 0; h < 8; ++h) {
    float v = OB[w][h * 65 + lane];
    bias_out[(size_t)h * NPAIR + wbase + lane] = mk ? v : -1e30f;
  }
}

// ---------------- K4: per (head, 8-row tile) attention + gate ----------------
// v2: 8 rows x 32 lanes; scores in registers; PV = per-lane float4 accumulation
// over its own 24 j's + 31-shuffle transpose-reduce. No SIM LDS, no barriers.
__global__ __launch_bounds__(256, 3) void k_attn(const float* __restrict__ q,
                                                 const float* __restrict__ k,
                                                 const float* __restrict__ v,
                                                 const float* __restrict__ gate,
                                                 const float* __restrict__ bias,
                                                 float* __restrict__ aout) {
  __shared__ __align__(16) float QS[256];
  int i0 = blockIdx.x * 8, h = blockIdx.y, t = threadIdx.x;
  int tr = t >> 5, tc = t & 31;
  QS[t] = q[((size_t)h * NT + i0 + tr) * DH + tc];   // row-group-coherent
  float4 qr[8];
#pragma unroll
  for (int e = 0; e < 8; ++e) qr[e] = *(float4*)&QS[tr * 32 + e * 4];
  const float* Kh = k + (size_t)h * NT * DH;
  const float* Vh = v + (size_t)h * NT * DH;
  const float* brow = bias + ((size_t)h * NT + i0 + tr) * NT;
  float sv[24];
  float mx = -3.4e38f;
#pragma unroll
  for (int it = 0; it < 24; ++it) {
    int j = it * 32 + tc;
    const float4* kr = (const float4*)(Kh + j * DH);
    float s = 0.f;
#pragma unroll
    for (int e = 0; e < 8; ++e) {
      float4 kv = kr[e];
      s += qr[e].x * kv.x + qr[e].y * kv.y + qr[e].z * kv.z + qr[e].w * kv.w;
    }
    s += brow[j];                     // q pre-scaled; bias carries mask fold
    sv[it] = s;
    mx = fmaxf(mx, s);
  }
#pragma unroll
  for (int m = 1; m < 32; m <<= 1) mx = fmaxf(mx, __shfl_xor(mx, m));
  float sum = 0.f;
#pragma unroll
  for (int it = 0; it < 24; ++it) {
    float p = __expf(sv[it] - mx);
    sv[it] = p;
    sum += p;
  }
#pragma unroll
  for (int m = 1; m < 32; m <<= 1) sum += __shfl_xor(sum, m);
  float inv = 1.f / sum;
  // PV: lane accumulates all 32 dims for its own 24 j's
  f32x4 acc[8];
#pragma unroll
  for (int e = 0; e < 8; ++e) acc[e] = (f32x4){0.f, 0.f, 0.f, 0.f};
#pragma unroll
  for (int it = 0; it < 24; ++it) {
    int j = it * 32 + tc;
    const f32x4* vr = (const f32x4*)(Vh + j * DH);
    f32x4 pv = (f32x4){sv[it], sv[it], sv[it], sv[it]};
#pragma unroll
    for (int e = 0; e < 8; ++e) acc[e] = __builtin_elementwise_fma(pv, vr[e], acc[e]);
  }
  // transpose-reduce: 32 dims x 32 lanes -> lane tc owns dim tc
  float a32[32];
#pragma unroll
  for (int e = 0; e < 8; ++e) {
    a32[e * 4 + 0] = acc[e].x; a32[e * 4 + 1] = acc[e].y;
    a32[e * 4 + 2] = acc[e].z; a32[e * 4 + 3] = acc[e].w;
  }
  bool L16 = (tc & 16) != 0, L8 = (tc & 8) != 0, L4 = (tc & 4) != 0,
       L2 = (tc & 2) != 0, L1 = (tc & 1) != 0;
  float b16[16];
#pragma unroll
  for (int i = 0; i < 16; ++i) {
    float send = L16 ? a32[i] : a32[i + 16];
    float keep = L16 ? a32[i + 16] : a32[i];
    b16[i] = keep + __shfl_xor(send, 16);
  }
  float c8[8];
#pragma unroll
  for (int i = 0; i < 8; ++i) {
    float send = L8 ? b16[i] : b16[i + 8];
    float keep = L8 ? b16[i + 8] : b16[i];
    c8[i] = keep + __shfl_xor(send, 8);
  }
  float d4[4];
#pragma unroll
  for (int i = 0; i < 4; ++i) {
    float send = L4 ? c8[i] : c8[i + 4];
    float keep = L4 ? c8[i + 4] : c8[i];
    d4[i] = keep + __shfl_xor(send, 4);
  }
  float e2[2];
#pragma unroll
  for (int i = 0; i < 2; ++i) {
    float send = L2 ? d4[i] : d4[i + 2];
    float keep = L2 ? d4[i + 2] : d4[i];
    e2[i] = keep + __shfl_xor(send, 2);
  }
  float send = L1 ? e2[0] : e2[1];
  float keep = L1 ? e2[1] : e2[0];
  float f1 = keep + __shfl_xor(send, 1);
  int i = i0 + tr;
  float gg = gate[i * ND + h * DH + tc];
  aout[i * ND + h * DH + tc] = f1 * inv * gg;
}

// ---------------- K5: aout @ w_out + b_out -> fp32 output ----------------
__global__ __launch_bounds__(256) void k_proj(const float* __restrict__ a,
                                              const float* __restrict__ w,
                                              const float* __restrict__ b,
                                              float* __restrict__ out) {
  __shared__ __align__(16) float As[16 * 64];
  __shared__ __align__(16) float Bs[16 * 64];
  int n0 = blockIdx.x * 64, i0 = blockIdx.y * 64, t = threadIdx.x;
  int tm = t >> 4, tn = t & 15;
  int sm = t >> 2, sk = (t & 3) * 4;
  int bk = t >> 4, bn = (t & 15) * 4;
  float acc[4][4] = {{0.f}};
  for (int k0 = 0; k0 < 256; k0 += 16) {
    float4 av = *(const float4*)&a[(i0 + sm) * 256 + k0 + sk];
    float4 bv = *(const float4*)&w[(k0 + bk) * 256 + n0 + bn];
    __syncthreads();
    As[(sk + 0) * 64 + sm] = av.x; As[(sk + 1) * 64 + sm] = av.y;
    As[(sk + 2) * 64 + sm] = av.z; As[(sk + 3) * 64 + sm] = av.w;
    *(float4*)&Bs[bk * 64 + bn] = bv;
    __syncthreads();
#pragma unroll
    for (int kk = 0; kk < 16; ++kk) {
      float4 a4 = *(float4*)&As[kk * 64 + tm * 4];
      float4 b4 = *(float4*)&Bs[kk * 64 + tn * 4];
      float ar[4] = {a4.x, a4.y, a4.z, a4.w};
      float br[4] = {b4.x, b4.y, b4.z, b4.w};
#pragma unroll
      for (int ii = 0; ii < 4; ++ii)
#pragma unroll
        for (int jj = 0; jj < 4; ++jj) acc[ii][jj] = fmaf(ar[ii], br[jj], acc[ii][jj]);
    }
  }
#pragma unroll
  for (int ii = 0; ii < 4; ++ii) {
    int i = i0 + tm * 4 + ii;
#pragma unroll
    for (int jj = 0; jj < 4; ++jj) {
      int o = n0 + tn * 4 + jj;
      out[i * 256 + o] = acc[ii][jj] + b[o];
    }
  }
}

extern "C" void kernel_launch(void* const* d_in, const int* in_sizes, int n_in,
                              void* d_out, int out_size, void* d_ws, size_t ws_size,
                              hipStream_t stream) {
  const float* node   = (const float*)d_in[0];
  const float* pair   = (const float*)d_in[1];
  const int*   mask   = (const int*)d_in[2];
  const float* ln_nw  = (const float*)d_in[3];
  const float* ln_nb  = (const float*)d_in[4];
  const float* ln_pw  = (const float*)d_in[5];
  const float* ln_pb  = (const float*)d_in[6];
  const float* w_qkv  = (const float*)d_in[7];
  const float* w_g    = (const float*)d_in[8];
  const float* b_g    = (const float*)d_in[9];
  const float* w_bias = (const float*)d_in[10];
  const float* w_out  = (const float*)d_in[11];
  const float* b_out  = (const float*)d_in[12];
  float* ws = (float*)d_ws;
  float* out = (float*)d_out;

  k_prep<<<1, 256, 0, stream>>>(ln_pw, ln_pb, w_bias, ws + WS_WPT, ws + WS_C01);
  k_pair_bias<<<NPAIR / 256, 256, 0, stream>>>(pair, mask, ws + WS_WPT, ws + WS_C01,
                                               ws + WS_BIAS);
  k_ln_node<<<NT, 256, 0, stream>>>(node, ln_nw, ln_nb, ws + WS_X);
  k_qkvg<<<dim3(16, 12), 256, 0, stream>>>(ws + WS_X, w_qkv, w_g, b_g, ws);
  k_attn<<<dim3(96, 8), 256, 0, stream>>>(ws + WS_Q, ws + WS_K, ws + WS_V,
                                          ws + WS_GATE, ws + WS_BIAS, ws + WS_AOUT);
  k_proj<<<dim3(4, 12), 256, 0, stream>>>(ws + WS_AOUT, w_out, b_out, out);
}

// Round 7
// 228.997 us; speedup vs baseline: 1.0335x; 1.0335x over previous
//
#include <hip/hip_runtime.h>
#include <hip/hip_bf16.h>

#define NT 768
#define ND 256
#define PD 128
#define NH 8
#define DH 32
#define NPAIR 589824   // 768*768

// workspace offsets (floats)
#define WS_X     0
#define WS_Q     196608
#define WS_K     393216
#define WS_V     589824
#define WS_GATE  786432
#define WS_AOUT  983040
#define WS_BIAS  1179648
#define WS_WPT   5898240   // 1024 floats: wpt[h][e] = ln_w[e]*wb[e][h]
#define WS_C01   5899264   // c0[0..7], c1[0..7]
// total = 5899280 floats = 23.6 MB

typedef float f32x2 __attribute__((ext_vector_type(2)));
typedef float f32x4 __attribute__((ext_vector_type(4)));

// ---------------- K0: precompute WPT, C0, C1 (one block) ----------------
__global__ __launch_bounds__(256) void k_prep(const float* __restrict__ lnw,
                                              const float* __restrict__ lnb,
                                              const float* __restrict__ wb,
                                              float* __restrict__ wpt,
                                              float* __restrict__ c01) {
  __shared__ float PS0[256], PS1[256];
  int t = threadIdx.x;
#pragma unroll
  for (int i = 0; i < 4; ++i) {
    int idx = t + 256 * i;
    int h = idx >> 7, e = idx & 127;
    wpt[h * 128 + e] = lnw[e] * wb[e * 8 + h];
  }
  int h = t & 7, seg = t >> 3;          // seg 0..31 covers e = 4*seg..+3
  float a0 = 0.f, a1 = 0.f;
#pragma unroll
  for (int k = 0; k < 4; ++k) {
    int e = seg * 4 + k;
    float wv = wb[e * 8 + h];
    a0 = fmaf(lnb[e], wv, a0);
    a1 = fmaf(lnw[e], wv, a1);
  }
  PS0[t] = a0; PS1[t] = a1;
  __syncthreads();
  if (t < 16) {
    int hh = t & 7; bool isc1 = t >= 8;
    float s = 0.f;
    for (int sg = 0; sg < 32; ++sg) s += (isc1 ? PS1 : PS0)[sg * 8 + hh];
    c01[t] = s;
  }
}

// ---------------- K1: LayerNorm(node) -> x ----------------
__global__ __launch_bounds__(256) void k_ln_node(const float* __restrict__ nf,
                                                 const float* __restrict__ w,
                                                 const float* __restrict__ b,
                                                 float* __restrict__ x) {
  int i = blockIdx.x, t = threadIdx.x;
  float v = nf[i * ND + t];
  float s1 = v, s2 = v * v;
#pragma unroll
  for (int m = 1; m < 64; m <<= 1) { s1 += __shfl_xor(s1, m); s2 += __shfl_xor(s2, m); }
  __shared__ float a1[4], a2[4];
  if ((t & 63) == 0) { a1[t >> 6] = s1; a2[t >> 6] = s2; }
  __syncthreads();
  s1 = a1[0] + a1[1] + a1[2] + a1[3];
  s2 = a2[0] + a2[1] + a2[2] + a2[3];
  float mu = s1 * (1.f / ND);
  float var = s2 * (1.f / ND) - mu * mu;
  float rs = rsqrtf(var + 1e-5f);
  x[i * ND + t] = (v - mu) * rs * w[t] + b[t];
}

// ---------------- K2: x @ [w_qkv | w_g] -> q,k,v (h,i,d) + sigmoid gate ----------------
__global__ __launch_bounds__(256) void k_qkvg(const float* __restrict__ x,
                                              const float* __restrict__ wqkv,
                                              const float* __restrict__ wg,
                                              const float* __restrict__ bg,
                                              float* __restrict__ ws) {
  __shared__ __align__(16) float As[16 * 64];
  __shared__ __align__(16) float Bs[16 * 64];
  int n0 = blockIdx.x * 64, i0 = blockIdx.y * 64, t = threadIdx.x;
  bool isg = (n0 >= 768);
  const float* W = isg ? wg : wqkv;
  int ldb = isg ? 256 : 768;
  int nc0 = isg ? n0 - 768 : n0;
  int tm = t >> 4, tn = t & 15;
  int sm = t >> 2, sk = (t & 3) * 4;
  int bk = t >> 4, bn = (t & 15) * 4;
  float acc[4][4] = {{0.f}};
  for (int k0 = 0; k0 < 256; k0 += 16) {
    float4 av = *(const float4*)&x[(i0 + sm) * 256 + k0 + sk];
    float4 bv = *(const float4*)&W[(size_t)(k0 + bk) * ldb + nc0 + bn];
    __syncthreads();
    As[(sk + 0) * 64 + sm] = av.x; As[(sk + 1) * 64 + sm] = av.y;
    As[(sk + 2) * 64 + sm] = av.z; As[(sk + 3) * 64 + sm] = av.w;
    *(float4*)&Bs[bk * 64 + bn] = bv;
    __syncthreads();
#pragma unroll
    for (int kk = 0; kk < 16; ++kk) {
      float4 a4 = *(float4*)&As[kk * 64 + tm * 4];
      float4 b4 = *(float4*)&Bs[kk * 64 + tn * 4];
      float ar[4] = {a4.x, a4.y, a4.z, a4.w};
      float br[4] = {b4.x, b4.y, b4.z, b4.w};
#pragma unroll
      for (int ii = 0; ii < 4; ++ii)
#pragma unroll
        for (int jj = 0; jj < 4; ++jj) acc[ii][jj] = fmaf(ar[ii], br[jj], acc[ii][jj]);
    }
  }
#pragma unroll
  for (int ii = 0; ii < 4; ++ii) {
    int i = i0 + tm * 4 + ii;
#pragma unroll
    for (int jj = 0; jj < 4; ++jj) {
      int o = n0 + tn * 4 + jj;
      float val = acc[ii][jj];
      if (!isg) {
        int which = o >> 8, inner = o & 255, h = inner >> 5, d = inner & 31;
        float* dst = ws + (which == 0 ? WS_Q : (which == 1 ? WS_K : WS_V));
        float sc = (which == 0) ? 0.17677669529663687f : 1.f;  // 1/sqrt(32) on q
        dst[(h * NT + i) * DH + d] = val * sc;
      } else {
        int inner = nc0 + tn * 4 + jj;
        val += bg[inner];
        ws[WS_GATE + i * ND + inner] = 1.f / (1.f + __expf(-val));
      }
    }
  }
}

// ---------------- K3: fused LN(pair) @ w_bias + mask fold -> bias (h,i,j) ----------------
// v5: one row per lane. s1/s2/d[8] all thread-local -> zero shuffles, zero LDS,
// zero barriers. wpt accessed with wave-uniform indices -> scalar loads (SGPR),
// v_fma takes the SGPR operand directly. Stores/mask lane-consecutive.
__global__ __launch_bounds__(256) void k_pair_bias(const float* __restrict__ pf,
                                                   const int* __restrict__ mask,
                                                   const float* __restrict__ wpt,
                                                   const float* __restrict__ c01,
                                                   float* __restrict__ bias_out) {
  size_t row = (size_t)blockIdx.x * 256 + threadIdx.x;
  const float* prow = pf + row * 128;
  f32x4 d[8];
#pragma unroll
  for (int h = 0; h < 8; ++h) d[h] = (f32x4){0.f, 0.f, 0.f, 0.f};
  f32x4 s1v = (f32x4){0.f, 0.f, 0.f, 0.f};
  f32x4 s2v = (f32x4){0.f, 0.f, 0.f, 0.f};
#pragma unroll
  for (int c = 0; c < 32; ++c) {
    f32x4 p = *(const f32x4*)(prow + c * 4);
    s1v += p;
    s2v = __builtin_elementwise_fma(p, p, s2v);
#pragma unroll
    for (int h = 0; h < 8; ++h) {
      // uniform (loop-counter) indices -> s_load, broadcast via SGPR operand
      f32x4 wv = *(const f32x4*)(wpt + h * 128 + c * 4);
      d[h] = __builtin_elementwise_fma(p, wv, d[h]);
    }
  }
  float s1 = (s1v.x + s1v.y) + (s1v.z + s1v.w);
  float s2 = (s2v.x + s2v.y) + (s2v.z + s2v.w);
  float mu = s1 * (1.f / 128.f);
  float var = s2 * (1.f / 128.f) - mu * mu;
  float rs = rsqrtf(var + 1e-5f);
  int mk = mask[row];
#pragma unroll
  for (int h = 0; h < 8; ++h) {
    float dot = (d[h].x + d[h].y) + (d[h].z + d[h].w);
    float bv = rs * (dot - mu * c01[8 + h]) + c01[h];
    bias_out[(size_t)h * NPAIR + row] = mk ? bv : -1e30f;
  }
}

// ---------------- K4: per (head, 8-row tile) attention + gate ----------------
// 256 threads = 8 rows x 32 lanes. Each wave owns 2 complete rows -> no barriers.
__global__ __launch_bounds__(256) void k_attn(const float* __restrict__ q,
                                              const float* __restrict__ k,
                                              const float* __restrict__ v,
                                              const float* __restrict__ gate,
                                              const float* __restrict__ bias,
                                              float* __restrict__ aout) {
  __shared__ __align__(16) float SIM[8 * 772];
  __shared__ __align__(16) float QS[256];
  int i0 = blockIdx.x * 8, h = blockIdx.y, t = threadIdx.x;
  int tr = t >> 5, tc = t & 31;
  QS[t] = q[((size_t)h * NT + i0 + tr) * DH + tc];   // t == tr*32+tc
  float4 qr[8];
#pragma unroll
  for (int e = 0; e < 8; ++e) qr[e] = *(float4*)&QS[tr * 32 + e * 4];
  const float* Kh = k + (size_t)h * NT * DH;
  const float* Vh = v + (size_t)h * NT * DH;
  const float* brow = bias + ((size_t)h * NT + i0 + tr) * NT;
  float sv[24];
  float mx = -3.4e38f;
#pragma unroll
  for (int it = 0; it < 24; ++it) {
    int j = it * 32 + tc;
    const float4* kr = (const float4*)(Kh + j * DH);
    float s = 0.f;
#pragma unroll
    for (int e = 0; e < 8; ++e) {
      float4 kv = kr[e];
      s += qr[e].x * kv.x + qr[e].y * kv.y + qr[e].z * kv.z + qr[e].w * kv.w;
    }
    s += brow[j];                     // q pre-scaled; bias carries mask fold
    sv[it] = s;
    mx = fmaxf(mx, s);
  }
#pragma unroll
  for (int m = 1; m < 32; m <<= 1) mx = fmaxf(mx, __shfl_xor(mx, m));
  float sum = 0.f;
#pragma unroll
  for (int it = 0; it < 24; ++it) {
    float p = __expf(sv[it] - mx);
    SIM[tr * 772 + it * 32 + tc] = p;
    sum += p;
  }
#pragma unroll
  for (int m = 1; m < 32; m <<= 1) sum += __shfl_xor(sum, m);
  float inv = 1.f / sum;
  float acc = 0.f;
#pragma unroll 8
  for (int j = 0; j < NT; ++j) {
    acc = fmaf(SIM[tr * 772 + j], Vh[j * DH + tc], acc);
  }
  acc *= inv;
  int i = i0 + tr;
  float gg = gate[i * ND + h * DH + tc];
  aout[i * ND + h * DH + tc] = acc * gg;
}

// ---------------- K5: aout @ w_out + b_out -> fp32 output ----------------
__global__ __launch_bounds__(256) void k_proj(const float* __restrict__ a,
                                              const float* __restrict__ w,
                                              const float* __restrict__ b,
                                              float* __restrict__ out) {
  __shared__ __align__(16) float As[16 * 64];
  __shared__ __align__(16) float Bs[16 * 64];
  int n0 = blockIdx.x * 64, i0 = blockIdx.y * 64, t = threadIdx.x;
  int tm = t >> 4, tn = t & 15;
  int sm = t >> 2, sk = (t & 3) * 4;
  int bk = t >> 4, bn = (t & 15) * 4;
  float acc[4][4] = {{0.f}};
  for (int k0 = 0; k0 < 256; k0 += 16) {
    float4 av = *(const float4*)&a[(i0 + sm) * 256 + k0 + sk];
    float4 bv = *(const float4*)&w[(k0 + bk) * 256 + n0 + bn];
    __syncthreads();
    As[(sk + 0) * 64 + sm] = av.x; As[(sk + 1) * 64 + sm] = av.y;
    As[(sk + 2) * 64 + sm] = av.z; As[(sk + 3) * 64 + sm] = av.w;
    *(float4*)&Bs[bk * 64 + bn] = bv;
    __syncthreads();
#pragma unroll
    for (int kk = 0; kk < 16; ++kk) {
      float4 a4 = *(float4*)&As[kk * 64 + tm * 4];
      float4 b4 = *(float4*)&Bs[kk * 64 + tn * 4];
      float ar[4] = {a4.x, a4.y, a4.z, a4.w};
      float br[4] = {b4.x, b4.y, b4.z, b4.w};
#pragma unroll
      for (int ii = 0; ii < 4; ++ii)
#pragma unroll
        for (int jj = 0; jj < 4; ++jj) acc[ii][jj] = fmaf(ar[ii], br[jj], acc[ii][jj]);
    }
  }
#pragma unroll
  for (int ii = 0; ii < 4; ++ii) {
    int i = i0 + tm * 4 + ii;
#pragma unroll
    for (int jj = 0; jj < 4; ++jj) {
      int o = n0 + tn * 4 + jj;
      out[i * 256 + o] = acc[ii][jj] + b[o];
    }
  }
}

extern "C" void kernel_launch(void* const* d_in, const int* in_sizes, int n_in,
                              void* d_out, int out_size, void* d_ws, size_t ws_size,
                              hipStream_t stream) {
  const float* node   = (const float*)d_in[0];
  const float* pair   = (const float*)d_in[1];
  const int*   mask   = (const int*)d_in[2];
  const float* ln_nw  = (const float*)d_in[3];
  const float* ln_nb  = (const float*)d_in[4];
  const float* ln_pw  = (const float*)d_in[5];
  const float* ln_pb  = (const float*)d_in[6];
  const float* w_qkv  = (const float*)d_in[7];
  const float* w_g    = (const float*)d_in[8];
  const float* b_g    = (const float*)d_in[9];
  const float* w_bias = (const float*)d_in[10];
  const float* w_out  = (const float*)d_in[11];
  const float* b_out  = (const float*)d_in[12];
  float* ws = (float*)d_ws;
  float* out = (float*)d_out;

  k_prep<<<1, 256, 0, stream>>>(ln_pw, ln_pb, w_bias, ws + WS_WPT, ws + WS_C01);
  k_pair_bias<<<NPAIR / 256, 256, 0, stream>>>(pair, mask, ws + WS_WPT, ws + WS_C01,
                                               ws + WS_BIAS);
  k_ln_node<<<NT, 256, 0, stream>>>(node, ln_nw, ln_nb, ws + WS_X);
  k_qkvg<<<dim3(16, 12), 256, 0, stream>>>(ws + WS_X, w_qkv, w_g, b_g, ws);
  k_attn<<<dim3(96, 8), 256, 0, stream>>>(ws + WS_Q, ws + WS_K, ws + WS_V,
                                          ws + WS_GATE, ws + WS_BIAS, ws + WS_AOUT);
  k_proj<<<dim3(4, 12), 256, 0, stream>>>(ws + WS_AOUT, w_out, b_out, out);
}

// Round 8
// 205.314 us; speedup vs baseline: 1.1527x; 1.1154x over previous
//
#include <hip/hip_runtime.h>
#include <hip/hip_bf16.h>

#define NT 768
#define ND 256
#define PD 128
#define NH 8
#define DH 32
#define NPAIR 589824   // 768*768

// workspace offsets (floats)
#define WS_X     0
#define WS_Q     196608
#define WS_K     393216
#define WS_V     589824
#define WS_GATE  786432
#define WS_AOUT  983040
#define WS_BIAS  1179648
#define WS_WPT   5898240   // 1024 floats: wpt[h][e] = ln_w[e]*wb[e][h]
#define WS_C01   5899264   // c0[0..7], c1[0..7]
// total = 5899280 floats = 23.6 MB

typedef float f32x4 __attribute__((ext_vector_type(4)));

// ---------------- K0: precompute WPT, C0, C1 (one block) ----------------
__global__ __launch_bounds__(256) void k_prep(const float* __restrict__ lnw,
                                              const float* __restrict__ lnb,
                                              const float* __restrict__ wb,
                                              float* __restrict__ wpt,
                                              float* __restrict__ c01) {
  __shared__ float PS0[256], PS1[256];
  int t = threadIdx.x;
#pragma unroll
  for (int i = 0; i < 4; ++i) {
    int idx = t + 256 * i;
    int h = idx >> 7, e = idx & 127;
    wpt[h * 128 + e] = lnw[e] * wb[e * 8 + h];
  }
  int h = t & 7, seg = t >> 3;          // seg 0..31 covers e = 4*seg..+3
  float a0 = 0.f, a1 = 0.f;
#pragma unroll
  for (int k = 0; k < 4; ++k) {
    int e = seg * 4 + k;
    float wv = wb[e * 8 + h];
    a0 = fmaf(lnb[e], wv, a0);
    a1 = fmaf(lnw[e], wv, a1);
  }
  PS0[t] = a0; PS1[t] = a1;
  __syncthreads();
  if (t < 16) {
    int hh = t & 7; bool isc1 = t >= 8;
    float s = 0.f;
    for (int sg = 0; sg < 32; ++sg) s += (isc1 ? PS1 : PS0)[sg * 8 + hh];
    c01[t] = s;
  }
}

// ---------------- K1: LayerNorm(node) -> x ----------------
__global__ __launch_bounds__(256) void k_ln_node(const float* __restrict__ nf,
                                                 const float* __restrict__ w,
                                                 const float* __restrict__ b,
                                                 float* __restrict__ x) {
  int i = blockIdx.x, t = threadIdx.x;
  float v = nf[i * ND + t];
  float s1 = v, s2 = v * v;
#pragma unroll
  for (int m = 1; m < 64; m <<= 1) { s1 += __shfl_xor(s1, m); s2 += __shfl_xor(s2, m); }
  __shared__ float a1[4], a2[4];
  if ((t & 63) == 0) { a1[t >> 6] = s1; a2[t >> 6] = s2; }
  __syncthreads();
  s1 = a1[0] + a1[1] + a1[2] + a1[3];
  s2 = a2[0] + a2[1] + a2[2] + a2[3];
  float mu = s1 * (1.f / ND);
  float var = s2 * (1.f / ND) - mu * mu;
  float rs = rsqrtf(var + 1e-5f);
  x[i * ND + t] = (v - mu) * rs * w[t] + b[t];
}

// ---------------- K2: x @ [w_qkv | w_g] -> q,k,v (h,i,d) + sigmoid gate ----------------
__global__ __launch_bounds__(256) void k_qkvg(const float* __restrict__ x,
                                              const float* __restrict__ wqkv,
                                              const float* __restrict__ wg,
                                              const float* __restrict__ bg,
                                              float* __restrict__ ws) {
  __shared__ __align__(16) float As[16 * 64];
  __shared__ __align__(16) float Bs[16 * 64];
  int n0 = blockIdx.x * 64, i0 = blockIdx.y * 64, t = threadIdx.x;
  bool isg = (n0 >= 768);
  const float* W = isg ? wg : wqkv;
  int ldb = isg ? 256 : 768;
  int nc0 = isg ? n0 - 768 : n0;
  int tm = t >> 4, tn = t & 15;
  int sm = t >> 2, sk = (t & 3) * 4;
  int bk = t >> 4, bn = (t & 15) * 4;
  float acc[4][4] = {{0.f}};
  for (int k0 = 0; k0 < 256; k0 += 16) {
    float4 av = *(const float4*)&x[(i0 + sm) * 256 + k0 + sk];
    float4 bv = *(const float4*)&W[(size_t)(k0 + bk) * ldb + nc0 + bn];
    __syncthreads();
    As[(sk + 0) * 64 + sm] = av.x; As[(sk + 1) * 64 + sm] = av.y;
    As[(sk + 2) * 64 + sm] = av.z; As[(sk + 3) * 64 + sm] = av.w;
    *(float4*)&Bs[bk * 64 + bn] = bv;
    __syncthreads();
#pragma unroll
    for (int kk = 0; kk < 16; ++kk) {
      float4 a4 = *(float4*)&As[kk * 64 + tm * 4];
      float4 b4 = *(float4*)&Bs[kk * 64 + tn * 4];
      float ar[4] = {a4.x, a4.y, a4.z, a4.w};
      float br[4] = {b4.x, b4.y, b4.z, b4.w};
#pragma unroll
      for (int ii = 0; ii < 4; ++ii)
#pragma unroll
        for (int jj = 0; jj < 4; ++jj) acc[ii][jj] = fmaf(ar[ii], br[jj], acc[ii][jj]);
    }
  }
#pragma unroll
  for (int ii = 0; ii < 4; ++ii) {
    int i = i0 + tm * 4 + ii;
#pragma unroll
    for (int jj = 0; jj < 4; ++jj) {
      int o = n0 + tn * 4 + jj;
      float val = acc[ii][jj];
      if (!isg) {
        int which = o >> 8, inner = o & 255, h = inner >> 5, d = inner & 31;
        float* dst = ws + (which == 0 ? WS_Q : (which == 1 ? WS_K : WS_V));
        float sc = (which == 0) ? 0.17677669529663687f : 1.f;  // 1/sqrt(32) on q
        dst[(h * NT + i) * DH + d] = val * sc;
      } else {
        int inner = nc0 + tn * 4 + jj;
        val += bg[inner];
        ws[WS_GATE + i * ND + inner] = 1.f / (1.f + __expf(-val));
      }
    }
  }
}

// ---------------- K3: fused LN(pair) @ w_bias + mask fold -> bias (h,i,j) ----------------
// v6: LDS tile transpose. Wave owns 64 rows; per 32-ch tile: coalesced global
// load (8 rows x 128B per instr) -> reg prefetch -> LDS [64][33] (stride 33:
// bank=(row+e)%32, 2-way free) -> each lane streams ITS row thread-local.
// Zero shuffles, zero barriers (wave-private LDS, in-order DS). wpt/c01 via SGPR.
__global__ __launch_bounds__(256) void k_pair_bias(const float* __restrict__ pf,
                                                   const int* __restrict__ mask,
                                                   const float* __restrict__ wpt,
                                                   const float* __restrict__ c01,
                                                   float* __restrict__ bias_out) {
  __shared__ float LT[4][64 * 33];      // 33.8 KB/block, wave-private quarters
  int t = threadIdx.x;
  int w = t >> 6, lane = t & 63;
  int lg = lane >> 3;                   // row subgroup 0..7
  int lc = lane & 7;                    // 16B chunk 0..7 within 32-ch tile
  size_t wbase = ((size_t)blockIdx.x * 4 + w) * 64;
  float* lds = &LT[w][0];

  f32x4 buf[8], nxt[8];
#pragma unroll
  for (int it = 0; it < 8; ++it)
    buf[it] = *(const f32x4*)(pf + (wbase + it * 8 + lg) * 128 + 0 * 32 + lc * 4);
#pragma unroll
  for (int it = 0; it < 8; ++it) {
    float* p = lds + (it * 8 + lg) * 33 + lc * 4;
    p[0] = buf[it].x; p[1] = buf[it].y; p[2] = buf[it].z; p[3] = buf[it].w;
  }

  float d0 = 0.f, d1 = 0.f, d2 = 0.f, d3 = 0.f;
  float d4 = 0.f, d5 = 0.f, d6 = 0.f, d7 = 0.f;
  float s1 = 0.f, s2 = 0.f;
#pragma unroll
  for (int cb = 0; cb < 4; ++cb) {
    if (cb < 3) {
#pragma unroll
      for (int it = 0; it < 8; ++it)
        nxt[it] = *(const f32x4*)(pf + (wbase + it * 8 + lg) * 128 + (cb + 1) * 32 + lc * 4);
    }
#pragma unroll
    for (int e = 0; e < 32; ++e) {
      float p = lds[lane * 33 + e];     // own row, bank=(lane+e)%32 -> 2-way free
      int ch = cb * 32 + e;
      s1 += p;
      s2 = fmaf(p, p, s2);
      d0 = fmaf(p, wpt[0 * 128 + ch], d0);   // uniform idx -> s_load (SGPR)
      d1 = fmaf(p, wpt[1 * 128 + ch], d1);
      d2 = fmaf(p, wpt[2 * 128 + ch], d2);
      d3 = fmaf(p, wpt[3 * 128 + ch], d3);
      d4 = fmaf(p, wpt[4 * 128 + ch], d4);
      d5 = fmaf(p, wpt[5 * 128 + ch], d5);
      d6 = fmaf(p, wpt[6 * 128 + ch], d6);
      d7 = fmaf(p, wpt[7 * 128 + ch], d7);
    }
    if (cb < 3) {
#pragma unroll
      for (int it = 0; it < 8; ++it) {
        float* p = lds + (it * 8 + lg) * 33 + lc * 4;
        p[0] = nxt[it].x; p[1] = nxt[it].y; p[2] = nxt[it].z; p[3] = nxt[it].w;
      }
    }
  }
  float mu = s1 * (1.f / 128.f);
  float var = s2 * (1.f / 128.f) - mu * mu;
  float rs = rsqrtf(var + 1e-5f);
  size_t row = wbase + lane;
  int mk = mask[row];
  float c1mu = mu;
  float dd[8] = {d0, d1, d2, d3, d4, d5, d6, d7};
#pragma unroll
  for (int h = 0; h < 8; ++h) {
    float bv = rs * (dd[h] - c1mu * c01[8 + h]) + c01[h];
    bias_out[(size_t)h * NPAIR + row] = mk ? bv : -1e30f;
  }
}

// ---------------- K4: per (head, 8-row tile) attention + gate ----------------
// 256 threads = 8 rows x 32 lanes. Each wave owns 2 complete rows -> no barriers.
__global__ __launch_bounds__(256) void k_attn(const float* __restrict__ q,
                                              const float* __restrict__ k,
                                              const float* __restrict__ v,
                                              const float* __restrict__ gate,
                                              const float* __restrict__ bias,
                                              float* __restrict__ aout) {
  __shared__ __align__(16) float SIM[8 * 772];
  __shared__ __align__(16) float QS[256];
  int i0 = blockIdx.x * 8, h = blockIdx.y, t = threadIdx.x;
  int tr = t >> 5, tc = t & 31;
  QS[t] = q[((size_t)h * NT + i0 + tr) * DH + tc];   // t == tr*32+tc
  float4 qr[8];
#pragma unroll
  for (int e = 0; e < 8; ++e) qr[e] = *(float4*)&QS[tr * 32 + e * 4];
  const float* Kh = k + (size_t)h * NT * DH;
  const float* Vh = v + (size_t)h * NT * DH;
  const float* brow = bias + ((size_t)h * NT + i0 + tr) * NT;
  float sv[24];
  float mx = -3.4e38f;
#pragma unroll
  for (int it = 0; it < 24; ++it) {
    int j = it * 32 + tc;
    const float4* kr = (const float4*)(Kh + j * DH);
    float s = 0.f;
#pragma unroll
    for (int e = 0; e < 8; ++e) {
      float4 kv = kr[e];
      s += qr[e].x * kv.x + qr[e].y * kv.y + qr[e].z * kv.z + qr[e].w * kv.w;
    }
    s += brow[j];                     // q pre-scaled; bias carries mask fold
    sv[it] = s;
    mx = fmaxf(mx, s);
  }
#pragma unroll
  for (int m = 1; m < 32; m <<= 1) mx = fmaxf(mx, __shfl_xor(mx, m));
  float sum = 0.f;
#pragma unroll
  for (int it = 0; it < 24; ++it) {
    float p = __expf(sv[it] - mx);
    SIM[tr * 772 + it * 32 + tc] = p;
    sum += p;
  }
#pragma unroll
  for (int m = 1; m < 32; m <<= 1) sum += __shfl_xor(sum, m);
  float inv = 1.f / sum;
  float acc = 0.f;
#pragma unroll 8
  for (int j = 0; j < NT; ++j) {
    acc = fmaf(SIM[tr * 772 + j], Vh[j * DH + tc], acc);
  }
  acc *= inv;
  int i = i0 + tr;
  float gg = gate[i * ND + h * DH + tc];
  aout[i * ND + h * DH + tc] = acc * gg;
}

// ---------------- K5: aout @ w_out + b_out -> fp32 output ----------------
__global__ __launch_bounds__(256) void k_proj(const float* __restrict__ a,
                                              const float* __restrict__ w,
                                              const float* __restrict__ b,
                                              float* __restrict__ out) {
  __shared__ __align__(16) float As[16 * 64];
  __shared__ __align__(16) float Bs[16 * 64];
  int n0 = blockIdx.x * 64, i0 = blockIdx.y * 64, t = threadIdx.x;
  int tm = t >> 4, tn = t & 15;
  int sm = t >> 2, sk = (t & 3) * 4;
  int bk = t >> 4, bn = (t & 15) * 4;
  float acc[4][4] = {{0.f}};
  for (int k0 = 0; k0 < 256; k0 += 16) {
    float4 av = *(const float4*)&a[(i0 + sm) * 256 + k0 + sk];
    float4 bv = *(const float4*)&w[(k0 + bk) * 256 + n0 + bn];
    __syncthreads();
    As[(sk + 0) * 64 + sm] = av.x; As[(sk + 1) * 64 + sm] = av.y;
    As[(sk + 2) * 64 + sm] = av.z; As[(sk + 3) * 64 + sm] = av.w;
    *(float4*)&Bs[bk * 64 + bn] = bv;
    __syncthreads();
#pragma unroll
    for (int kk = 0; kk < 16; ++kk) {
      float4 a4 = *(float4*)&As[kk * 64 + tm * 4];
      float4 b4 = *(float4*)&Bs[kk * 64 + tn * 4];
      float ar[4] = {a4.x, a4.y, a4.z, a4.w};
      float br[4] = {b4.x, b4.y, b4.z, b4.w};
#pragma unroll
      for (int ii = 0; ii < 4; ++ii)
#pragma unroll
        for (int jj = 0; jj < 4; ++jj) acc[ii][jj] = fmaf(ar[ii], br[jj], acc[ii][jj]);
    }
  }
#pragma unroll
  for (int ii = 0; ii < 4; ++ii) {
    int i = i0 + tm * 4 + ii;
#pragma unroll
    for (int jj = 0; jj < 4; ++jj) {
      int o = n0 + tn * 4 + jj;
      out[i * 256 + o] = acc[ii][jj] + b[o];
    }
  }
}

extern "C" void kernel_launch(void* const* d_in, const int* in_sizes, int n_in,
                              void* d_out, int out_size, void* d_ws, size_t ws_size,
                              hipStream_t stream) {
  const float* node   = (const float*)d_in[0];
  const float* pair   = (const float*)d_in[1];
  const int*   mask   = (const int*)d_in[2];
  const float* ln_nw  = (const float*)d_in[3];
  const float* ln_nb  = (const float*)d_in[4];
  const float* ln_pw  = (const float*)d_in[5];
  const float* ln_pb  = (const float*)d_in[6];
  const float* w_qkv  = (const float*)d_in[7];
  const float* w_g    = (const float*)d_in[8];
  const float* b_g    = (const float*)d_in[9];
  const float* w_bias = (const float*)d_in[10];
  const float* w_out  = (const float*)d_in[11];
  const float* b_out  = (const float*)d_in[12];
  float* ws = (float*)d_ws;
  float* out = (float*)d_out;

  k_prep<<<1, 256, 0, stream>>>(ln_pw, ln_pb, w_bias, ws + WS_WPT, ws + WS_C01);
  k_pair_bias<<<NPAIR / 256, 256, 0, stream>>>(pair, mask, ws + WS_WPT, ws + WS_C01,
                                               ws + WS_BIAS);
  k_ln_node<<<NT, 256, 0, stream>>>(node, ln_nw, ln_nb, ws + WS_X);
  k_qkvg<<<dim3(16, 12), 256, 0, stream>>>(ws + WS_X, w_qkv, w_g, b_g, ws);
  k_attn<<<dim3(96, 8), 256, 0, stream>>>(ws + WS_Q, ws + WS_K, ws + WS_V,
                                          ws + WS_GATE, ws + WS_BIAS, ws + WS_AOUT);
  k_proj<<<dim3(4, 12), 256, 0, stream>>>(ws + WS_AOUT, w_out, b_out, out);
}